// Round 4
// baseline (58.528 us; speedup 1.0000x reference)
//
#include <hip/hip_runtime.h>
#include <math.h>

#define BATCH 128
#define NPWM 512
#define LEN 1000
#define KSZ 19
#define NPOS 982
#define NEXT 1024     // 2*NPWM (fwd + revcomp interleaved: f_ext = 2*f + strand)
#define KSLOT 80      // kk padded 19->20, slot = kk*4 + c  (32x32x16 needs K % 16 == 0)

typedef __bf16 bf16x4 __attribute__((ext_vector_type(4)));
typedef __bf16 bf16x8 __attribute__((ext_vector_type(8)));
typedef float  f32x16 __attribute__((ext_vector_type(16)));

#define MFMA32(a, b, c) __builtin_amdgcn_mfma_f32_32x32x16_bf16(a, b, c, 0, 0, 0)

// ---- prepack W: (512,4,19) fp32 -> (1024,80) bf16 hi/lo, zeros at pad slots ----
__global__ __launch_bounds__(256)
void prepack_w(const float* __restrict__ w, __bf16* __restrict__ whi, __bf16* __restrict__ wlo)
{
    int idx = blockIdx.x * 256 + threadIdx.x;
    if (idx >= NEXT * KSLOT) return;
    int fe = idx / KSLOT;
    int t  = idx - fe * KSLOT;
    int kk = t >> 2;
    int c  = t & 3;
    int f      = fe >> 1;
    int strand = fe & 1;
    float v = 0.0f;
    if (kk < KSZ)
        v = strand ? w[f*76 + (3-c)*19 + (18-kk)]   // reverse-complement
                   : w[f*76 + c*19 + kk];
    __bf16 h = (__bf16)v;
    whi[idx] = h;
    wlo[idx] = (__bf16)(v - (float)h);
}

// ---- main: im2col bf16-split GEMM, 32x32x16 MFMA, fused position-max ----
// block = 4 waves; wave owns 64 f_ext (fg=2 tiles of 32), scans all 992 positions.
// grid = (128 batches, 4 f-blocks of 256 f_ext) = 512 blocks = 2/CU exactly.
__global__ __launch_bounds__(256, 2)
void pwm_mfma(const float* __restrict__ x,
              const __bf16* __restrict__ whi,
              const __bf16* __restrict__ wlo,
              float* __restrict__ out)
{
    __shared__ __align__(16) __bf16 H[4096];   // x hi, [pos][c], pos 0..1023 (tail 0)
    __shared__ __align__(16) __bf16 L[4096];   // x lo
    __shared__ float red[256];

    const int tid   = threadIdx.x;
    const int b     = blockIdx.x;
    const int ftile = blockIdx.y;   // 0..3
    const int lane  = tid & 63;
    const int wave  = tid >> 6;
    const int col   = lane & 31;    // A-row / B-col / D-col index
    const int gh    = lane >> 5;    // k-group half

    // stage x[b] -> bf16 hi/lo, position-major [pos][channel]; 8B LDS writes
    for (int i = tid; i < 1024; i += 256) {
        bf16x4 hv, lv;
        #pragma unroll
        for (int c = 0; c < 4; ++c) {
            float v = (i < LEN) ? x[(size_t)b*4000 + c*1000 + i] : 0.0f;
            __bf16 h = (__bf16)v;
            hv[c] = h;
            lv[c] = (__bf16)(v - (float)h);
        }
        *(bf16x4*)(H + i*4) = hv;
        *(bf16x4*)(L + i*4) = lv;
    }

    // A fragments (W) -> regs: lane holds W[f0+fg*32+col][k = t*16 + gh*8 + j]
    bf16x8 wah[2][5], wal[2][5];
    {
        const int f0 = ftile*256 + wave*64;
        #pragma unroll
        for (int fg = 0; fg < 2; ++fg)
            #pragma unroll
            for (int t = 0; t < 5; ++t) {
                const size_t o = (size_t)(f0 + fg*32 + col)*KSLOT + t*16 + gh*8;
                wah[fg][t] = *(const bf16x8*)(whi + o);
                wal[fg][t] = *(const bf16x8*)(wlo + o);
            }
    }
    __syncthreads();

    f32x16 m0, m1;
    #pragma unroll
    for (int r = 0; r < 16; ++r) { m0[r] = -INFINITY; m1[r] = -INFINITY; }

    // B element base: slot k = t*16 + gh*8 + j  ->  x[(pos + t*4 + 2*gh)*4 + ...]
    for (int it = 0; it < 31; ++it) {
        f32x16 a0 = {}, a1 = {};
        const int ebase = it*128 + (col + 2*gh)*4;
        #pragma unroll
        for (int t = 0; t < 5; ++t) {
            const __bf16* pH = H + ebase + t*16;
            const __bf16* pL = L + ebase + t*16;
            bf16x4 h0 = *(const bf16x4*)(pH);
            bf16x4 h1 = *(const bf16x4*)(pH + 4);
            bf16x4 l0 = *(const bf16x4*)(pL);
            bf16x4 l1 = *(const bf16x4*)(pL + 4);
            bf16x8 bh = __builtin_shufflevector(h0, h1, 0,1,2,3,4,5,6,7);
            bf16x8 bl = __builtin_shufflevector(l0, l1, 0,1,2,3,4,5,6,7);
            // 3-term split, a0/a1 chains interleaved (dep distance 2)
            a0 = MFMA32(wah[0][t], bh, a0);
            a1 = MFMA32(wah[1][t], bh, a1);
            a0 = MFMA32(wal[0][t], bh, a0);
            a1 = MFMA32(wal[1][t], bh, a1);
            a0 = MFMA32(wah[0][t], bl, a0);
            a1 = MFMA32(wah[1][t], bl, a1);
        }
        // positions this iter: pos = it*32 + col; mask pos >= 982 (it==30, col>=22)
        if (it < 30 || col < 22) {
            #pragma unroll
            for (int r = 0; r < 16; ++r) {
                m0[r] = fmaxf(m0[r], a0[r]);
                m1[r] = fmaxf(m1[r], a1[r]);
            }
        }
    }

    // reduce over the 32 position-columns (lanes within each 32-half)
    #pragma unroll
    for (int off = 1; off <= 16; off <<= 1) {
        #pragma unroll
        for (int r = 0; r < 16; ++r) {
            m0[r] = fmaxf(m0[r], __shfl_xor(m0[r], off, 64));
            m1[r] = fmaxf(m1[r], __shfl_xor(m1[r], off, 64));
        }
    }

    // D row (filter within 32-tile) = (r&3) + 8*(r>>2) + 4*gh
    if (col == 0) {
        #pragma unroll
        for (int r = 0; r < 16; ++r) {
            const int row = (r & 3) + 8*(r >> 2) + 4*gh;
            red[wave*64 + row]      = m0[r];
            red[wave*64 + 32 + row] = m1[r];
        }
    }
    __syncthreads();
    if (tid < 128)   // combine strand pairs (f_ext = 2f, 2f+1)
        out[(size_t)b*NPWM + ftile*128 + tid] = fmaxf(red[2*tid], red[2*tid+1]);
}

extern "C" void kernel_launch(void* const* d_in, const int* in_sizes, int n_in,
                              void* d_out, int out_size, void* d_ws, size_t ws_size,
                              hipStream_t stream)
{
    const float* x = (const float*)d_in[0];   // (128, 4, 1000)
    const float* w = (const float*)d_in[1];   // (512, 4, 19)
    float* out = (float*)d_out;               // (128, 512)

    __bf16* whi = (__bf16*)d_ws;              // 1024*80 bf16
    __bf16* wlo = whi + NEXT*KSLOT;

    prepack_w<<<dim3((NEXT*KSLOT + 255)/256), 256, 0, stream>>>(w, whi, wlo);
    pwm_mfma<<<dim3(BATCH, 4), 256, 0, stream>>>(x, whi, wlo, out);
}